// Round 17
// baseline (305.556 us; speedup 1.0000x reference)
//
#include <hip/hip_runtime.h>
#include <hip/hip_bf16.h>
#include <cstdint>
#include <cstddef>

#define TPB 256

typedef __attribute__((ext_vector_type(8))) short bf16x8;
typedef __attribute__((ext_vector_type(8))) unsigned short ushort8;
typedef __attribute__((ext_vector_type(4))) float f32x4;

#if defined(__has_builtin)
#  if __has_builtin(__builtin_amdgcn_fdot2_f32_bf16) && __has_builtin(__builtin_amdgcn_perm)
#    define HAVE_BF16DOT2 1
#  endif
#endif
#ifndef HAVE_BF16DOT2
#  define HAVE_BF16DOT2 0
#endif

#if HAVE_BF16DOT2
typedef __attribute__((ext_vector_type(2))) __bf16 bfv2;
static __device__ __forceinline__ bfv2 u2bf2(unsigned u) {
  union { unsigned u; bfv2 v; } c; c.u = u; return c.v;
}
#endif

static __device__ __forceinline__ float bf2f(unsigned short u) {
  union { unsigned int i; float f; } c;
  c.i = ((unsigned int)u) << 16;
  return c.f;
}
static __device__ __forceinline__ unsigned short f2us(float v) {
  __hip_bfloat16 b = __float2bfloat16(v);
  return *(unsigned short*)&b;
}

// ---------------------------------------------------------------------------
// prep: zero counts/fill arrays; block 0 also detects edge dtype
// ---------------------------------------------------------------------------
__global__ void prep_kernel(const unsigned int* __restrict__ ei, int* __restrict__ flag,
                            int* __restrict__ counts, int* __restrict__ fillc, int n) {
  int i = blockIdx.x * TPB + threadIdx.x;
  if (i < n) { counts[i] = 0; fillc[i] = 0; }
  if (blockIdx.x == 0) {
    __shared__ int any32;
    if (threadIdx.x == 0) any32 = 0;
    __syncthreads();
    for (int k = threadIdx.x; k < 1024; k += TPB)
      if (ei[2 * k + 1] != 0u) any32 = 1;
    __syncthreads();
    if (threadIdx.x == 0) *flag = any32;   // 1 -> int32 data, 0 -> int64
  }
}

// decode edges (+ self loops) and count dst degrees in one pass
__global__ void decode_count_kernel(const void* __restrict__ raw, const int* __restrict__ flag,
                                    int* __restrict__ src, int* __restrict__ dst,
                                    int* __restrict__ counts, int E, int n) {
  int i = blockIdx.x * TPB + threadIdx.x;
  int tot = E + n;
  if (i >= tot) return;
  int s, d;
  if (i < E) {
    if (*flag) {
      const int* p = (const int*)raw;
      s = p[i]; d = p[E + i];
    } else {
      const long long* p = (const long long*)raw;
      s = (int)p[i]; d = (int)p[E + i];
    }
  } else {
    s = i - E; d = i - E;
  }
  src[i] = s; dst[i] = d;
  atomicAdd(&counts[d], 1);
}

__global__ void scan_kernel(const int* __restrict__ counts, int* __restrict__ row_ptr, int n) {
  __shared__ int part[TPB];
  int tid = threadIdx.x;
  int chunk = (n + TPB - 1) / TPB;
  int begin = tid * chunk;
  int end = begin + chunk; if (end > n) end = n;
  int s = 0;
  for (int i = begin; i < end && i < n; i++) s += counts[i];
  part[tid] = s;
  __syncthreads();
  for (int off = 1; off < TPB; off <<= 1) {
    int v = (tid >= off) ? part[tid - off] : 0;
    __syncthreads();
    part[tid] += v;
    __syncthreads();
  }
  int base = (tid == 0) ? 0 : part[tid - 1];
  for (int i = begin; i < end && i < n; i++) { row_ptr[i] = base; base += counts[i]; }
  if (tid == TPB - 1) row_ptr[n] = base;
}

__global__ void fill_kernel(const int* __restrict__ src, const int* __restrict__ dst,
                            const int* __restrict__ row_ptr, int* __restrict__ fill,
                            int* __restrict__ sorted_src, int etot) {
  int i = blockIdx.x * TPB + threadIdx.x;
  if (i >= etot) return;
  int d = dst[i];
  int pos = row_ptr[d] + atomicAdd(&fill[d], 1);
  sorted_src[pos] = src[i];
}

// ---------------------------------------------------------------------------
// fp32 -> bf16 convert (linear, for x)
// ---------------------------------------------------------------------------
__global__ void f32_to_bf16_kernel(const float* __restrict__ in, __hip_bfloat16* __restrict__ out, int n) {
  int i = blockIdx.x * TPB + threadIdx.x;
  if (i < n) out[i] = __float2bfloat16(in[i]);
}

// ---------------------------------------------------------------------------
// Batched weight conversion: all 5 transposes (fp32 [K][N] -> bf16 [N][K]).
// ---------------------------------------------------------------------------
__global__ void convert_weights_kernel(
    const float* __restrict__ Wp, const float* __restrict__ W0,
    const float* __restrict__ W1, const float* __restrict__ W2,
    const float* __restrict__ Wr,
    __hip_bfloat16* __restrict__ WpT, __hip_bfloat16* __restrict__ W0T,
    __hip_bfloat16* __restrict__ W1T, __hip_bfloat16* __restrict__ WrW2T) {
  const int b = blockIdx.x;
  const float* src; __hip_bfloat16* dst; int K, N, t;
  if (b < 8)        { src = Wp; dst = WpT; K = 64;  N = 128;  t = b; }
  else if (b < 136) { src = W0; dst = W0T; K = 128; N = 1024; t = b - 8; }
  else if (b < 264) { src = W1; dst = W1T; K = 128; N = 1024; t = b - 136; }
  else if (b < 272) { src = W2; dst = WrW2T + 64 * 128; K = 128; N = 64; t = b - 264; }
  else              { src = Wr; dst = WrW2T;            K = 128; N = 64; t = b - 272; }

  __shared__ float tile[32][33];
  const int kt = (K + 31) / 32;
  const int k0 = (t % kt) * 32, n0 = (t / kt) * 32;
  const int tx = threadIdx.x & 31, ty = threadIdx.x >> 5;   // 32 x 8
  for (int r = ty; r < 32; r += 8) {
    int k = k0 + r, n = n0 + tx;
    tile[r][tx] = (k < K && n < N) ? src[(size_t)k * N + n] : 0.f;
  }
  __syncthreads();
  for (int r = ty; r < 32; r += 8) {
    int n = n0 + r, k = k0 + tx;
    if (n < N && k < K) dst[(size_t)n * K + k] = __float2bfloat16(tile[tx][r]);
  }
}

// ---------------------------------------------------------------------------
// bf16 MFMA GEMM with pre-transposed B: C[M,N] = A[M,K] @ Bt[N,K]^T (+bias).
// Tile 128(M) x 128(N), BK=32, 4 waves; each wave owns 32 rows (2 A-frags
// x 8 B-frags = 16 MFMA per K-step). Optional f32 C / bf16 Cb; optional
// fused es/ed; optional bnsum zeroing.
// ---------------------------------------------------------------------------
__global__ __launch_bounds__(256) void gemm_bf16t_kernel(
    const short* __restrict__ A, const short* __restrict__ Bt,
    const float* __restrict__ bias, float* __restrict__ C,
    __hip_bfloat16* __restrict__ Cb, int M, int Ncols, int K,
    const float* __restrict__ asrc, const float* __restrict__ adst,
    float* __restrict__ es_out, float* __restrict__ ed_out, int H, int hshift,
    float* __restrict__ bn_zero, int bn_len) {
  __shared__ short As[128][40];   // [row][k], 80B row stride
  __shared__ short Bs[128][40];   // [col][k]

  const int tid = threadIdx.x;
  if (bn_zero && blockIdx.x == 0 && blockIdx.y == 0 && tid < bn_len) bn_zero[tid] = 0.f;

  const int lane = tid & 63;
  const int w = tid >> 6;
  const int bm = blockIdx.x * 128;
  const int bn = blockIdx.y * 128;

  f32x4 acc[2][8];
#pragma unroll
  for (int f = 0; f < 2; f++)
#pragma unroll
    for (int nt = 0; nt < 8; nt++) acc[f][nt] = (f32x4){0.f, 0.f, 0.f, 0.f};

  const int arow = tid >> 1;          // 0..127
  const int akk = (tid & 1) << 4;     // 0,16

  for (int k0 = 0; k0 < K; k0 += 32) {
    {
      int gr = bm + arow;
      if (gr < M) {
        const short* ap = &A[(size_t)gr * K + k0 + akk];
        *(bf16x8*)&As[arow][akk]     = *(const bf16x8*)ap;
        *(bf16x8*)&As[arow][akk + 8] = *(const bf16x8*)(ap + 8);
      } else {
        bf16x8 z = {0, 0, 0, 0, 0, 0, 0, 0};
        *(bf16x8*)&As[arow][akk] = z;
        *(bf16x8*)&As[arow][akk + 8] = z;
      }
    }
    {
      int gbn = bn + arow;
      if (gbn < Ncols) {
        const short* bp = &Bt[(size_t)gbn * K + k0 + akk];
        *(bf16x8*)&Bs[arow][akk]     = *(const bf16x8*)bp;
        *(bf16x8*)&Bs[arow][akk + 8] = *(const bf16x8*)(bp + 8);
      } else {
        bf16x8 z = {0, 0, 0, 0, 0, 0, 0, 0};
        *(bf16x8*)&Bs[arow][akk] = z;
        *(bf16x8*)&Bs[arow][akk + 8] = z;
      }
    }
    __syncthreads();

    bf16x8 a0 = *(const bf16x8*)&As[w * 32 + (lane & 15)][(lane >> 4) * 8];
    bf16x8 a1 = *(const bf16x8*)&As[w * 32 + 16 + (lane & 15)][(lane >> 4) * 8];
#pragma unroll
    for (int nt = 0; nt < 8; nt++) {
      bf16x8 b = *(const bf16x8*)&Bs[nt * 16 + (lane & 15)][(lane >> 4) * 8];
      acc[0][nt] = __builtin_amdgcn_mfma_f32_16x16x32_bf16(a0, b, acc[0][nt], 0, 0, 0);
      acc[1][nt] = __builtin_amdgcn_mfma_f32_16x16x32_bf16(a1, b, acc[1][nt], 0, 0, 0);
    }
    __syncthreads();
  }

  float p1[2][4] = {{0.f, 0.f, 0.f, 0.f}, {0.f, 0.f, 0.f, 0.f}};
  float p2[2][4] = {{0.f, 0.f, 0.f, 0.f}, {0.f, 0.f, 0.f, 0.f}};

#pragma unroll
  for (int nt = 0; nt < 8; nt++) {
    int gc = bn + nt * 16 + (lane & 15);
    if (gc >= Ncols) continue;
    float bv = bias ? bias[gc] : 0.f;
    float asv = es_out ? asrc[gc] : 0.f;
    float adv = es_out ? adst[gc] : 0.f;
#pragma unroll
    for (int f = 0; f < 2; f++) {
#pragma unroll
      for (int q = 0; q < 4; q++) {
        int gr = bm + w * 32 + f * 16 + (lane >> 4) * 4 + q;
        if (gr < M) {
          float val = acc[f][nt][q] + bv;
          if (C) C[(size_t)gr * Ncols + gc] = val;
          if (Cb) Cb[(size_t)gr * Ncols + gc] = __float2bfloat16(val);
          p1[f][q] += val * asv;
          p2[f][q] += val * adv;
        }
      }
    }
  }

  if (es_out) {
    const int head = bn >> hshift;
#pragma unroll
    for (int f = 0; f < 2; f++) {
#pragma unroll
      for (int q = 0; q < 4; q++) {
        float s1 = p1[f][q], s2 = p2[f][q];
        s1 += __shfl_xor(s1, 1); s2 += __shfl_xor(s2, 1);
        s1 += __shfl_xor(s1, 2); s2 += __shfl_xor(s2, 2);
        s1 += __shfl_xor(s1, 4); s2 += __shfl_xor(s2, 4);
        s1 += __shfl_xor(s1, 8); s2 += __shfl_xor(s2, 8);
        int gr = bm + w * 32 + f * 16 + (lane >> 4) * 4 + q;
        if ((lane & 15) == 0 && gr < M) {
          es_out[(size_t)gr * H + head] = s1;
          ed_out[(size_t)gr * H + head] = s2;
        }
      }
    }
  }
}

// ---------------------------------------------------------------------------
// Head-partitioned gather WITH FUSED SOFTMAX (fdot2 fast path).
// ---------------------------------------------------------------------------
__global__ __launch_bounds__(256) void gat_gather_head_kernel(
    const int* __restrict__ row_ptr, const int* __restrict__ srcs,
    const unsigned short* __restrict__ gb, const float* __restrict__ es,
    const float* __restrict__ ed, unsigned short* __restrict__ partial,
    int n, int nb) {
  const int h = blockIdx.x & 7;
  const int nblk = blockIdx.x >> 3;
  const int wave = threadIdx.x >> 6, lane = threadIdx.x & 63;

  __shared__ int2 swlds[4][64];

  const int per = (n + nb - 1) / nb;
  const int v1 = min((nblk + 1) * per, n);
  const unsigned short* gsl = gb + h * 128;
  unsigned short* pout = partial + (size_t)h * n * 128;
  const int g = lane >> 4;                   // edge slot 0..3
  const int c8 = (lane & 15) * 8;            // 8-channel offset within head
  const char* gbase = (const char*)gsl + (c8 << 1);

#if HAVE_BF16DOT2
#define STORE_W(sv, wv) make_int2((sv) << 11, (int)f2us(wv))
#else
#define STORE_W(sv, wv) make_int2((sv) << 11, __float_as_int(wv))
#endif

  for (int v = nblk * per + wave; v < v1; v += 4) {
    const int begin = row_ptr[v];
    const int deg = row_ptr[v + 1] - begin;
    const float edv = ed[(size_t)v * 8 + h];
    float acc[8];
#pragma unroll
    for (int k = 0; k < 8; k++) acc[k] = 0.f;

    auto gather16 = [&](int j0) {
      int2 e0 = swlds[wave][j0 + g];
      int2 e1 = swlds[wave][j0 + 4 + g];
      int2 e2 = swlds[wave][j0 + 8 + g];
      int2 e3 = swlds[wave][j0 + 12 + g];
      uint4 u0 = *(const uint4*)(gbase + (unsigned)e0.x);
      uint4 u1 = *(const uint4*)(gbase + (unsigned)e1.x);
      uint4 u2 = *(const uint4*)(gbase + (unsigned)e2.x);
      uint4 u3 = *(const uint4*)(gbase + (unsigned)e3.x);
#if HAVE_BF16DOT2
      bfv2 w01 = u2bf2(((unsigned)e0.y & 0xffffu) | ((unsigned)e1.y << 16));
      bfv2 w23 = u2bf2(((unsigned)e2.y & 0xffffu) | ((unsigned)e3.y << 16));
#define DOT2W(wa, wb, k0)                                                        \
      acc[k0]     = __builtin_amdgcn_fdot2_f32_bf16(                             \
          u2bf2(__builtin_amdgcn_perm(wb, wa, 0x05040100u)), w01, acc[k0], false); \
      acc[k0 + 1] = __builtin_amdgcn_fdot2_f32_bf16(                             \
          u2bf2(__builtin_amdgcn_perm(wb, wa, 0x07060302u)), w01, acc[k0 + 1], false);
#define DOT2X(wa, wb, k0)                                                        \
      acc[k0]     = __builtin_amdgcn_fdot2_f32_bf16(                             \
          u2bf2(__builtin_amdgcn_perm(wb, wa, 0x05040100u)), w23, acc[k0], false); \
      acc[k0 + 1] = __builtin_amdgcn_fdot2_f32_bf16(                             \
          u2bf2(__builtin_amdgcn_perm(wb, wa, 0x07060302u)), w23, acc[k0 + 1], false);
      DOT2W(u0.x, u1.x, 0) DOT2W(u0.y, u1.y, 2) DOT2W(u0.z, u1.z, 4) DOT2W(u0.w, u1.w, 6)
      DOT2X(u2.x, u3.x, 0) DOT2X(u2.y, u3.y, 2) DOT2X(u2.z, u3.z, 4) DOT2X(u2.w, u3.w, 6)
#undef DOT2W
#undef DOT2X
#else
      float w0 = __int_as_float(e0.y), w1 = __int_as_float(e1.y);
      float w2 = __int_as_float(e2.y), w3 = __int_as_float(e3.y);
      const ushort8 s0 = *(const ushort8*)&u0;
      const ushort8 s1 = *(const ushort8*)&u1;
      const ushort8 s2 = *(const ushort8*)&u2;
      const ushort8 s3 = *(const ushort8*)&u3;
#pragma unroll
      for (int k = 0; k < 8; k++) {
        acc[k] += w0 * bf2f(s0[k]) + w1 * bf2f(s1[k])
                + w2 * bf2f(s2[k]) + w3 * bf2f(s3[k]);
      }
#endif
    };

    if (deg <= 64) {
      int sv = 0; float a = -1e30f;
      if (lane < deg) {
        sv = srcs[begin + lane];
        float t = es[(size_t)sv * 8 + h] + edv;
        a = t > 0.f ? t : 0.2f * t;
      }
      float m = a;
#pragma unroll
      for (int off = 32; off > 0; off >>= 1) m = fmaxf(m, __shfl_xor(m, off));
      float p = __expf(a - m);
      float ds = p;
#pragma unroll
      for (int off = 32; off > 0; off >>= 1) ds += __shfl_xor(ds, off);
      float wv = p * (1.0f / (ds + 1e-16f));
      swlds[wave][lane] = STORE_W(sv, wv);

      const int npad = (deg + 15) & ~15;
      for (int j0 = 0; j0 < npad; j0 += 16) gather16(j0);
    } else {
      float m = -1e30f;
      for (int base = 0; base < deg; base += 64) {
        if (base + lane < deg) {
          int s = srcs[begin + base + lane];
          float t = es[(size_t)s * 8 + h] + edv;
          t = t > 0.f ? t : 0.2f * t;
          m = fmaxf(m, t);
        }
      }
#pragma unroll
      for (int off = 32; off > 0; off >>= 1) m = fmaxf(m, __shfl_xor(m, off));
      float ds = 0.f;
      for (int base = 0; base < deg; base += 64) {
        if (base + lane < deg) {
          int s = srcs[begin + base + lane];
          float t = es[(size_t)s * 8 + h] + edv;
          t = t > 0.f ? t : 0.2f * t;
          ds += __expf(t - m);
        }
      }
#pragma unroll
      for (int off = 32; off > 0; off >>= 1) ds += __shfl_xor(ds, off);
      const float invd = 1.0f / (ds + 1e-16f);

      for (int base = 0; base < deg; base += 64) {
        const int cnt = min(64, deg - base);
        int sv = 0; float wv = 0.f;
        if (lane < cnt) {
          sv = srcs[begin + base + lane];
          float t = es[(size_t)sv * 8 + h] + edv;
          t = t > 0.f ? t : 0.2f * t;
          wv = __expf(t - m) * invd;
        }
        swlds[wave][lane] = STORE_W(sv, wv);
        const int npad = (cnt + 15) & ~15;
        for (int j0 = 0; j0 < npad; j0 += 16) gather16(j0);
      }
    }

#pragma unroll
    for (int k = 0; k < 8; k++) {
      acc[k] += __shfl_xor(acc[k], 16);
      acc[k] += __shfl_xor(acc[k], 32);
    }
    if (lane < 16) {
      unsigned int o[4];
#pragma unroll
      for (int k = 0; k < 4; k++)
        o[k] = (unsigned int)f2us(acc[2 * k]) | ((unsigned int)f2us(acc[2 * k + 1]) << 16);
      *(uint4*)&pout[(size_t)v * 128 + c8] = *(uint4*)o;
    }
  }
#undef STORE_W
}

// ---------------------------------------------------------------------------
// Fused: reduce 8 head partials -> out, plus BN column sums.
// ---------------------------------------------------------------------------
__global__ __launch_bounds__(256) void gat_reduce_bn_kernel(
    const unsigned short* __restrict__ partial, const float* __restrict__ bias,
    float* __restrict__ out, float* __restrict__ sums, int n) {
  const int t = threadIdx.x;
  const int stride = gridDim.x * TPB;
  float s0 = 0.f, q0 = 0.f, s1 = 0.f, q1 = 0.f;
  for (int idx = blockIdx.x * TPB + t; idx < n * 64; idx += stride) {
    int v = idx >> 6, c = (idx & 63) * 2;
    float sx = 0.f, sy = 0.f;
#pragma unroll
    for (int h = 0; h < 8; h++) {
      unsigned int u = *(const unsigned int*)&partial[(size_t)h * n * 128 + (size_t)v * 128 + c];
      sx += bf2f((unsigned short)u);
      sy += bf2f((unsigned short)(u >> 16));
    }
    float x0 = sx * 0.125f + bias[c];
    float x1 = sy * 0.125f + bias[c + 1];
    out[(size_t)v * 128 + c]     = x0;
    out[(size_t)v * 128 + c + 1] = x1;
    s0 += x0; q0 += x0 * x0;
    s1 += x1; q1 += x1 * x1;
  }
  __shared__ float ls0[TPB], lq0[TPB], ls1[TPB], lq1[TPB];
  ls0[t] = s0; lq0[t] = q0; ls1[t] = s1; lq1[t] = q1;
  __syncthreads();
  if (t < 64) {
    float S0 = ls0[t] + ls0[t + 64] + ls0[t + 128] + ls0[t + 192];
    float Q0 = lq0[t] + lq0[t + 64] + lq0[t + 128] + lq0[t + 192];
    float S1 = ls1[t] + ls1[t + 64] + ls1[t + 128] + ls1[t + 192];
    float Q1 = lq1[t] + lq1[t + 64] + lq1[t + 128] + lq1[t + 192];
    int c = t * 2;
    atomicAdd(&sums[c], S0);
    atomicAdd(&sums[128 + c], Q0);
    atomicAdd(&sums[c + 1], S1);
    atomicAdd(&sums[128 + c + 1], Q1);
  }
}

// ---------------------------------------------------------------------------
// Layer-2 aggregation (H=1, C=64): one WAVE per dst node, dense g[N][64].
// ---------------------------------------------------------------------------
__global__ __launch_bounds__(256) void gat_aggregate1_kernel(
    const int* __restrict__ row_ptr, const int* __restrict__ srcs,
    const float* __restrict__ g, const float* __restrict__ es,
    const float* __restrict__ ed, const float* __restrict__ bias,
    float* __restrict__ out, int n) {
  const int wave = threadIdx.x >> 6;
  const int lane = threadIdx.x & 63;
  const int v = blockIdx.x * 4 + wave;

  __shared__ int2 swlds[4][64];

  if (v >= n) return;

  const int begin = row_ptr[v];
  const int deg = row_ptr[v + 1] - begin;
  const float edv = ed[v];
  const char* gbase = (const char*)g + lane * 4;

  float acc = 0.f;

  auto gather8 = [&](int j0) {
    int2 e0 = swlds[wave][j0 + 0], e1 = swlds[wave][j0 + 1];
    int2 e2 = swlds[wave][j0 + 2], e3 = swlds[wave][j0 + 3];
    int2 e4 = swlds[wave][j0 + 4], e5 = swlds[wave][j0 + 5];
    int2 e6 = swlds[wave][j0 + 6], e7 = swlds[wave][j0 + 7];
    float f0 = *(const float*)(gbase + (unsigned)e0.x);
    float f1 = *(const float*)(gbase + (unsigned)e1.x);
    float f2 = *(const float*)(gbase + (unsigned)e2.x);
    float f3 = *(const float*)(gbase + (unsigned)e3.x);
    float f4 = *(const float*)(gbase + (unsigned)e4.x);
    float f5 = *(const float*)(gbase + (unsigned)e5.x);
    float f6 = *(const float*)(gbase + (unsigned)e6.x);
    float f7 = *(const float*)(gbase + (unsigned)e7.x);
    acc += (__int_as_float(e0.y) * f0 + __int_as_float(e1.y) * f1)
         + (__int_as_float(e2.y) * f2 + __int_as_float(e3.y) * f3)
         + (__int_as_float(e4.y) * f4 + __int_as_float(e5.y) * f5)
         + (__int_as_float(e6.y) * f6 + __int_as_float(e7.y) * f7);
  };

  if (deg <= 64) {
    float a = -1e30f;
    int s = 0;
    if (lane < deg) {
      s = srcs[begin + lane];
      float t = es[s] + edv;
      a = t > 0.f ? t : 0.2f * t;
    }
    float m = a;
#pragma unroll
    for (int off = 32; off > 0; off >>= 1) m = fmaxf(m, __shfl_xor(m, off));
    float p = __expf(a - m);
    float dsum = p;
#pragma unroll
    for (int off = 32; off > 0; off >>= 1) dsum += __shfl_xor(dsum, off);
    const float invd = 1.0f / (dsum + 1e-16f);
    swlds[wave][lane] = make_int2(s << 8, __float_as_int(p * invd));

    const int npad = (deg + 7) & ~7;
    for (int j0 = 0; j0 < npad; j0 += 8) gather8(j0);
  } else {
    float pm = -1e30f;
    for (int j = lane; j < deg; j += 64) {
      float a = es[srcs[begin + j]] + edv;
      a = a > 0.f ? a : 0.2f * a;
      pm = fmaxf(pm, a);
    }
#pragma unroll
    for (int off = 32; off > 0; off >>= 1) pm = fmaxf(pm, __shfl_xor(pm, off));
    float ps = 0.f;
    for (int j = lane; j < deg; j += 64) {
      float a = es[srcs[begin + j]] + edv;
      a = a > 0.f ? a : 0.2f * a;
      ps += __expf(a - pm);
    }
#pragma unroll
    for (int off = 32; off > 0; off >>= 1) ps += __shfl_xor(ps, off);
    const float invd = 1.0f / (ps + 1e-16f);

    for (int base = 0; base < deg; base += 64) {
      int cnt = min(64, deg - base);
      float wv = 0.f; int s = 0;
      if (lane < cnt) {
        s = srcs[begin + base + lane];
        float a = es[s] + edv;
        a = a > 0.f ? a : 0.2f * a;
        wv = __expf(a - pm) * invd;
      }
      swlds[wave][lane] = make_int2(s << 8, __float_as_int(wv));
      const int npad = (cnt + 7) & ~7;
      for (int j0 = 0; j0 < npad; j0 += 8) gather8(j0);
    }
  }
  out[(size_t)v * 64 + lane] = acc + bias[lane];
}

// ---------------------------------------------------------------------------
// BN column stats (layer-2 only)
// ---------------------------------------------------------------------------
template <int C>
__global__ void bn_stats_kernel(const float* __restrict__ x, int n, float* __restrict__ sums) {
  constexpr int T = 256;
  constexpr int RPI = T / C;
  constexpr int ITER = 8;
  constexpr int ROWS = RPI * ITER;
  int c = threadIdx.x % C;
  int r0 = threadIdx.x / C;
  int rowBase = blockIdx.x * ROWS;
  float s = 0.f, q = 0.f;
  for (int it = 0; it < ITER; ++it) {
    int r = rowBase + it * RPI + r0;
    if (r < n) {
      float v = x[(size_t)r * C + c];
      s += v; q += v * v;
    }
  }
  __shared__ float ls[T], lq[T];
  ls[threadIdx.x] = s; lq[threadIdx.x] = q;
  __syncthreads();
  if (threadIdx.x < C) {
    float ts = 0.f, tq = 0.f;
    for (int r = 0; r < RPI; ++r) { ts += ls[c + r * C]; tq += lq[c + r * C]; }
    atomicAdd(&sums[c], ts);
    atomicAdd(&sums[C + c], tq);
  }
}

// ---------------------------------------------------------------------------
// out = elu(bn(x)) + res ; optional bf16 copy of out. res strided.
// ---------------------------------------------------------------------------
template <int C>
__global__ void bn_elu_res_kernel(const float* __restrict__ x, const float* __restrict__ sums,
                                  const float* __restrict__ gamma, const float* __restrict__ beta,
                                  const float* __restrict__ res, int res_stride,
                                  float* __restrict__ out, __hip_bfloat16* __restrict__ outb, int n) {
  int i = blockIdx.x * TPB + threadIdx.x;
  if (i >= n * C) return;
  int c = i % C;
  float inv_n = 1.0f / (float)n;
  float mu = sums[c] * inv_n;
  float var = sums[C + c] * inv_n - mu * mu;
  float y = (x[i] - mu) * rsqrtf(var + 1e-5f) * gamma[c] + beta[c];
  y = y > 0.f ? y : expm1f(y);
  y += res[(size_t)(i / C) * res_stride + c];
  out[i] = y;
  if (outb) outb[i] = __float2bfloat16(y);
}

// ---------------------------------------------------------------------------
// host launch
// ---------------------------------------------------------------------------
extern "C" void kernel_launch(void* const* d_in, const int* in_sizes, int n_in,
                              void* d_out, int out_size, void* d_ws, size_t ws_size,
                              hipStream_t stream) {
  const float* x   = (const float*)d_in[0];
  const void*  ei  = d_in[1];
  const float* Wp  = (const float*)d_in[2];
  const float* bp  = (const float*)d_in[3];
  const float* W0  = (const float*)d_in[4];
  const float* as0 = (const float*)d_in[5];
  const float* ad0 = (const float*)d_in[6];
  const float* b0  = (const float*)d_in[7];
  const float* g0  = (const float*)d_in[8];
  const float* be0 = (const float*)d_in[9];
  const float* W1  = (const float*)d_in[10];
  const float* as1 = (const float*)d_in[11];
  const float* ad1 = (const float*)d_in[12];
  const float* b1  = (const float*)d_in[13];
  const float* g1  = (const float*)d_in[14];
  const float* be1 = (const float*)d_in[15];
  const float* W2  = (const float*)d_in[16];
  const float* as2 = (const float*)d_in[17];
  const float* ad2 = (const float*)d_in[18];
  const float* b2  = (const float*)d_in[19];
  const float* g2  = (const float*)d_in[20];
  const float* be2 = (const float*)d_in[21];
  const float* Wr  = (const float*)d_in[22];
  const float* br  = (const float*)d_in[23];

  const int N = in_sizes[0] / 64;       // 10000
  const int E = in_sizes[1] / 2;        // 160000
  const int ETOT = E + N;

  char* wsp = (char*)d_ws;
  size_t off = 0;
  auto alloc = [&](size_t bytes) -> void* {
    void* p = wsp + off;
    off += (bytes + 255) & ~(size_t)255;
    return p;
  };
  int*   flag    = (int*)alloc(4);
  int*   e_src   = (int*)alloc((size_t)ETOT * 4);
  int*   e_dst   = (int*)alloc((size_t)ETOT * 4);
  int*   counts  = (int*)alloc((size_t)N * 4);
  int*   fillc   = (int*)alloc((size_t)N * 4);
  int*   row_ptr = (int*)alloc((size_t)(N + 1) * 4);
  int*   s_src   = (int*)alloc((size_t)ETOT * 4);
  float* hA      = (float*)alloc((size_t)N * 128 * 4);
  float* hB      = (float*)alloc((size_t)N * 128 * 4);
  float* gat     = (float*)alloc((size_t)N * 128 * 4);
  float* es      = (float*)alloc((size_t)N * 8 * 4);
  float* ed      = (float*)alloc((size_t)N * 8 * 4);
  float* bnsum   = (float*)alloc(2 * 128 * 4);
  __hip_bfloat16* gbufb = (__hip_bfloat16*)alloc((size_t)N * 1024 * 2);  // big-layer g (bf16)
  float* gbuf    = (float*)gbufb;                                   // layer-2 g (f32, aliased)
  unsigned short* partial = (unsigned short*)alloc((size_t)N * 1024 * 2); // [8][N][128] bf16
  __hip_bfloat16* xb  = (__hip_bfloat16*)alloc((size_t)N * 64 * 2);
  __hip_bfloat16* hAb = (__hip_bfloat16*)alloc((size_t)N * 128 * 2);
  __hip_bfloat16* hBb = (__hip_bfloat16*)alloc((size_t)N * 128 * 2);
  __hip_bfloat16* WpT = (__hip_bfloat16*)alloc((size_t)128 * 64 * 2);    // [128][64]
  __hip_bfloat16* W0T = (__hip_bfloat16*)alloc((size_t)1024 * 128 * 2);  // [1024][128]
  __hip_bfloat16* W1T = (__hip_bfloat16*)alloc((size_t)1024 * 128 * 2);
  __hip_bfloat16* WrW2T = (__hip_bfloat16*)alloc((size_t)128 * 128 * 2); // [Wr rows 0-63 | W2 rows 64-127]

  const int egrid = (ETOT + TPB - 1) / TPB;
  const int mgrid = (N + 127) / 128;    // 79 (BM=128)
  const int NB = 512;                   // node-blocks for head-gather (4096 blocks)
  auto cgrid = [](int n) { return (n + TPB - 1) / TPB; };

  // ---- graph prep ----
  prep_kernel<<<cgrid(N), TPB, 0, stream>>>((const unsigned int*)ei, flag, counts, fillc, N);
  decode_count_kernel<<<egrid, TPB, 0, stream>>>(ei, flag, e_src, e_dst, counts, E, N);
  scan_kernel<<<1, TPB, 0, stream>>>(counts, row_ptr, N);
  fill_kernel<<<egrid, TPB, 0, stream>>>(e_src, e_dst, row_ptr, fillc, s_src, ETOT);

  // ---- conversions (batched) ----
  f32_to_bf16_kernel<<<cgrid(N * 64), TPB, 0, stream>>>(x, xb, N * 64);
  convert_weights_kernel<<<280, 256, 0, stream>>>(Wp, W0, W1, W2, Wr, WpT, W0T, W1T, WrW2T);

  // ---- projection: hA = x @ Wp + bp (also bf16 copy hAb) ----
  gemm_bf16t_kernel<<<dim3(mgrid, 1), 256, 0, stream>>>(
      (const short*)xb, (const short*)WpT, bp, hA, hAb, N, 128, 64,
      nullptr, nullptr, nullptr, nullptr, 1, 7, nullptr, 0);

  // ---- layer 0 ----
  gemm_bf16t_kernel<<<dim3(mgrid, 8), 256, 0, stream>>>(
      (const short*)hAb, (const short*)W0T, nullptr, nullptr, gbufb, N, 1024, 128,
      as0, ad0, es, ed, 8, 7, bnsum, 256);
  gat_gather_head_kernel<<<8 * NB, 256, 0, stream>>>(
      row_ptr, s_src, (const unsigned short*)gbufb, es, ed, partial, N, NB);
  gat_reduce_bn_kernel<<<512, 256, 0, stream>>>(partial, b0, gat, bnsum, N);
  bn_elu_res_kernel<128><<<cgrid(N * 128), TPB, 0, stream>>>(
      gat, bnsum, g0, be0, hA, 128, hB, hBb, N);

  // ---- layer 1 ----
  gemm_bf16t_kernel<<<dim3(mgrid, 8), 256, 0, stream>>>(
      (const short*)hBb, (const short*)W1T, nullptr, nullptr, gbufb, N, 1024, 128,
      as1, ad1, es, ed, 8, 7, bnsum, 256);
  gat_gather_head_kernel<<<8 * NB, 256, 0, stream>>>(
      row_ptr, s_src, (const unsigned short*)gbufb, es, ed, partial, N, NB);
  gat_reduce_bn_kernel<<<512, 256, 0, stream>>>(partial, b1, gat, bnsum, N);
  bn_elu_res_kernel<128><<<cgrid(N * 128), TPB, 0, stream>>>(
      gat, bnsum, g1, be1, hB, 128, hA, hAb, N);

  // ---- layer 2 (H=1, C=64): two dense GEMMs (Wr half / W2 half of WrW2T) ----
  gemm_bf16t_kernel<<<dim3(mgrid, 1), 256, 0, stream>>>(
      (const short*)hAb, (const short*)WrW2T, br, hB, nullptr, N, 64, 128,
      nullptr, nullptr, nullptr, nullptr, 1, 7, nullptr, 0);              // hr -> hB[N][64]
  gemm_bf16t_kernel<<<dim3(mgrid, 1), 256, 0, stream>>>(
      (const short*)hAb, (const short*)(WrW2T + 64 * 128), nullptr, gbuf, nullptr, N, 64, 128,
      as2, ad2, es, ed, 1, 6, bnsum, 128);                                // g -> gbuf[N][64]
  gat_aggregate1_kernel<<<(N + 3) / 4, 256, 0, stream>>>(
      row_ptr, s_src, gbuf, es, ed, b2, gat, N);
  bn_stats_kernel<64><<<(N + 31) / 32, 256, 0, stream>>>(gat, N, bnsum);
  bn_elu_res_kernel<64><<<cgrid(N * 64), TPB, 0, stream>>>(
      gat, bnsum, g2, be2, hB, 64, (float*)d_out, nullptr, N);
}

// Round 18
// 284.110 us; speedup vs baseline: 1.0755x; 1.0755x over previous
//
#include <hip/hip_runtime.h>
#include <hip/hip_bf16.h>
#include <cstdint>
#include <cstddef>

#define TPB 256

typedef __attribute__((ext_vector_type(8))) short bf16x8;
typedef __attribute__((ext_vector_type(8))) unsigned short ushort8;
typedef __attribute__((ext_vector_type(4))) float f32x4;

#if defined(__has_builtin)
#  if __has_builtin(__builtin_amdgcn_fdot2_f32_bf16) && __has_builtin(__builtin_amdgcn_perm)
#    define HAVE_BF16DOT2 1
#  endif
#endif
#ifndef HAVE_BF16DOT2
#  define HAVE_BF16DOT2 0
#endif

#if HAVE_BF16DOT2
typedef __attribute__((ext_vector_type(2))) __bf16 bfv2;
static __device__ __forceinline__ bfv2 u2bf2(unsigned u) {
  union { unsigned u; bfv2 v; } c; c.u = u; return c.v;
}
#endif

static __device__ __forceinline__ float bf2f(unsigned short u) {
  union { unsigned int i; float f; } c;
  c.i = ((unsigned int)u) << 16;
  return c.f;
}
static __device__ __forceinline__ unsigned short f2us(float v) {
  __hip_bfloat16 b = __float2bfloat16(v);
  return *(unsigned short*)&b;
}

// ---------------------------------------------------------------------------
// prep: zero counts/fill arrays; block 0 also detects edge dtype
// ---------------------------------------------------------------------------
__global__ void prep_kernel(const unsigned int* __restrict__ ei, int* __restrict__ flag,
                            int* __restrict__ counts, int* __restrict__ fillc, int n) {
  int i = blockIdx.x * TPB + threadIdx.x;
  if (i < n) { counts[i] = 0; fillc[i] = 0; }
  if (blockIdx.x == 0) {
    __shared__ int any32;
    if (threadIdx.x == 0) any32 = 0;
    __syncthreads();
    for (int k = threadIdx.x; k < 1024; k += TPB)
      if (ei[2 * k + 1] != 0u) any32 = 1;
    __syncthreads();
    if (threadIdx.x == 0) *flag = any32;   // 1 -> int32 data, 0 -> int64
  }
}

// decode edges (+ self loops) and count dst degrees in one pass
__global__ void decode_count_kernel(const void* __restrict__ raw, const int* __restrict__ flag,
                                    int* __restrict__ src, int* __restrict__ dst,
                                    int* __restrict__ counts, int E, int n) {
  int i = blockIdx.x * TPB + threadIdx.x;
  int tot = E + n;
  if (i >= tot) return;
  int s, d;
  if (i < E) {
    if (*flag) {
      const int* p = (const int*)raw;
      s = p[i]; d = p[E + i];
    } else {
      const long long* p = (const long long*)raw;
      s = (int)p[i]; d = (int)p[E + i];
    }
  } else {
    s = i - E; d = i - E;
  }
  src[i] = s; dst[i] = d;
  atomicAdd(&counts[d], 1);
}

__global__ void scan_kernel(const int* __restrict__ counts, int* __restrict__ row_ptr, int n) {
  __shared__ int part[TPB];
  int tid = threadIdx.x;
  int chunk = (n + TPB - 1) / TPB;
  int begin = tid * chunk;
  int end = begin + chunk; if (end > n) end = n;
  int s = 0;
  for (int i = begin; i < end && i < n; i++) s += counts[i];
  part[tid] = s;
  __syncthreads();
  for (int off = 1; off < TPB; off <<= 1) {
    int v = (tid >= off) ? part[tid - off] : 0;
    __syncthreads();
    part[tid] += v;
    __syncthreads();
  }
  int base = (tid == 0) ? 0 : part[tid - 1];
  for (int i = begin; i < end && i < n; i++) { row_ptr[i] = base; base += counts[i]; }
  if (tid == TPB - 1) row_ptr[n] = base;
}

__global__ void fill_kernel(const int* __restrict__ src, const int* __restrict__ dst,
                            const int* __restrict__ row_ptr, int* __restrict__ fill,
                            int* __restrict__ sorted_src, int etot) {
  int i = blockIdx.x * TPB + threadIdx.x;
  if (i >= etot) return;
  int d = dst[i];
  int pos = row_ptr[d] + atomicAdd(&fill[d], 1);
  sorted_src[pos] = src[i];
}

// ---------------------------------------------------------------------------
// fp32 -> bf16 convert (linear, for x)
// ---------------------------------------------------------------------------
__global__ void f32_to_bf16_kernel(const float* __restrict__ in, __hip_bfloat16* __restrict__ out, int n) {
  int i = blockIdx.x * TPB + threadIdx.x;
  if (i < n) out[i] = __float2bfloat16(in[i]);
}

// ---------------------------------------------------------------------------
// Batched weight conversion: all 5 transposes (fp32 [K][N] -> bf16 [N][K]).
// ---------------------------------------------------------------------------
__global__ void convert_weights_kernel(
    const float* __restrict__ Wp, const float* __restrict__ W0,
    const float* __restrict__ W1, const float* __restrict__ W2,
    const float* __restrict__ Wr,
    __hip_bfloat16* __restrict__ WpT, __hip_bfloat16* __restrict__ W0T,
    __hip_bfloat16* __restrict__ W1T, __hip_bfloat16* __restrict__ WrW2T) {
  const int b = blockIdx.x;
  const float* src; __hip_bfloat16* dst; int K, N, t;
  if (b < 8)        { src = Wp; dst = WpT; K = 64;  N = 128;  t = b; }
  else if (b < 136) { src = W0; dst = W0T; K = 128; N = 1024; t = b - 8; }
  else if (b < 264) { src = W1; dst = W1T; K = 128; N = 1024; t = b - 136; }
  else if (b < 272) { src = W2; dst = WrW2T + 64 * 128; K = 128; N = 64; t = b - 264; }
  else              { src = Wr; dst = WrW2T;            K = 128; N = 64; t = b - 272; }

  __shared__ float tile[32][33];
  const int kt = (K + 31) / 32;
  const int k0 = (t % kt) * 32, n0 = (t / kt) * 32;
  const int tx = threadIdx.x & 31, ty = threadIdx.x >> 5;   // 32 x 8
  for (int r = ty; r < 32; r += 8) {
    int k = k0 + r, n = n0 + tx;
    tile[r][tx] = (k < K && n < N) ? src[(size_t)k * N + n] : 0.f;
  }
  __syncthreads();
  for (int r = ty; r < 32; r += 8) {
    int n = n0 + r, k = k0 + tx;
    if (n < N && k < K) dst[(size_t)n * K + k] = __float2bfloat16(tile[tx][r]);
  }
}

// ---------------------------------------------------------------------------
// bf16 MFMA GEMM with pre-transposed B: C[M,N] = A[M,K] @ Bt[N,K]^T (+bias).
// Tile 64(M) x 128(N), BK=32, 4 waves, mfma_f32_16x16x32_bf16.
// Optional f32 C / bf16 Cb outputs; optional fused es/ed per head block;
// optional bnsum zeroing (block (0,0)).
// ---------------------------------------------------------------------------
__global__ __launch_bounds__(256) void gemm_bf16t_kernel(
    const short* __restrict__ A, const short* __restrict__ Bt,
    const float* __restrict__ bias, float* __restrict__ C,
    __hip_bfloat16* __restrict__ Cb, int M, int Ncols, int K,
    const float* __restrict__ asrc, const float* __restrict__ adst,
    float* __restrict__ es_out, float* __restrict__ ed_out, int H, int hshift,
    float* __restrict__ bn_zero, int bn_len) {
  __shared__ short As[64][40];    // [row][k], 80B row stride
  __shared__ short Bs[128][40];   // [col][k]

  const int tid = threadIdx.x;
  if (bn_zero && blockIdx.x == 0 && blockIdx.y == 0 && tid < bn_len) bn_zero[tid] = 0.f;

  const int lane = tid & 63;
  const int w = tid >> 6;
  const int bm = blockIdx.x * 64;
  const int bn = blockIdx.y * 128;

  f32x4 acc[8];
#pragma unroll
  for (int nt = 0; nt < 8; nt++) acc[nt] = (f32x4){0.f, 0.f, 0.f, 0.f};

  const int arow = tid >> 2;          // 0..63
  const int akk = (tid & 3) << 3;     // 0,8,16,24
  const int brow = tid >> 1;          // 0..127
  const int bkk = (tid & 1) << 4;     // 0,16

  for (int k0 = 0; k0 < K; k0 += 32) {
    {
      int gr = bm + arow;
      if (gr < M) {
        *(bf16x8*)&As[arow][akk] = *(const bf16x8*)&A[(size_t)gr * K + k0 + akk];
      } else {
        bf16x8 z = {0, 0, 0, 0, 0, 0, 0, 0};
        *(bf16x8*)&As[arow][akk] = z;
      }
    }
    {
      int gbn = bn + brow;
      if (gbn < Ncols) {
        const short* bp = &Bt[(size_t)gbn * K + k0 + bkk];
        *(bf16x8*)&Bs[brow][bkk]     = *(const bf16x8*)bp;
        *(bf16x8*)&Bs[brow][bkk + 8] = *(const bf16x8*)(bp + 8);
      } else {
        bf16x8 z = {0, 0, 0, 0, 0, 0, 0, 0};
        *(bf16x8*)&Bs[brow][bkk] = z;
        *(bf16x8*)&Bs[brow][bkk + 8] = z;
      }
    }
    __syncthreads();

    bf16x8 a = *(const bf16x8*)&As[w * 16 + (lane & 15)][(lane >> 4) * 8];
#pragma unroll
    for (int nt = 0; nt < 8; nt++) {
      bf16x8 b = *(const bf16x8*)&Bs[nt * 16 + (lane & 15)][(lane >> 4) * 8];
      acc[nt] = __builtin_amdgcn_mfma_f32_16x16x32_bf16(a, b, acc[nt], 0, 0, 0);
    }
    __syncthreads();
  }

  float p1[4] = {0.f, 0.f, 0.f, 0.f};
  float p2[4] = {0.f, 0.f, 0.f, 0.f};

#pragma unroll
  for (int nt = 0; nt < 8; nt++) {
    int gc = bn + nt * 16 + (lane & 15);
    if (gc >= Ncols) continue;
    float bv = bias ? bias[gc] : 0.f;
    float asv = es_out ? asrc[gc] : 0.f;
    float adv = es_out ? adst[gc] : 0.f;
#pragma unroll
    for (int q = 0; q < 4; q++) {
      int gr = bm + w * 16 + (lane >> 4) * 4 + q;
      if (gr < M) {
        float val = acc[nt][q] + bv;
        if (C) C[(size_t)gr * Ncols + gc] = val;
        if (Cb) Cb[(size_t)gr * Ncols + gc] = __float2bfloat16(val);
        p1[q] += val * asv;
        p2[q] += val * adv;
      }
    }
  }

  if (es_out) {
    const int head = bn >> hshift;
#pragma unroll
    for (int q = 0; q < 4; q++) {
      float s1 = p1[q], s2 = p2[q];
      s1 += __shfl_xor(s1, 1); s2 += __shfl_xor(s2, 1);
      s1 += __shfl_xor(s1, 2); s2 += __shfl_xor(s2, 2);
      s1 += __shfl_xor(s1, 4); s2 += __shfl_xor(s2, 4);
      s1 += __shfl_xor(s1, 8); s2 += __shfl_xor(s2, 8);
      int gr = bm + w * 16 + (lane >> 4) * 4 + q;
      if ((lane & 15) == 0 && gr < M) {
        es_out[(size_t)gr * H + head] = s1;
        ed_out[(size_t)gr * H + head] = s2;
      }
    }
  }
}

// ---------------------------------------------------------------------------
// Head-partitioned gather WITH FUSED SOFTMAX (fdot2 fast path).
// ---------------------------------------------------------------------------
__global__ __launch_bounds__(256) void gat_gather_head_kernel(
    const int* __restrict__ row_ptr, const int* __restrict__ srcs,
    const unsigned short* __restrict__ gb, const float* __restrict__ es,
    const float* __restrict__ ed, unsigned short* __restrict__ partial,
    int n, int nb) {
  const int h = blockIdx.x & 7;
  const int nblk = blockIdx.x >> 3;
  const int wave = threadIdx.x >> 6, lane = threadIdx.x & 63;

  __shared__ int2 swlds[4][64];

  const int per = (n + nb - 1) / nb;
  const int v1 = min((nblk + 1) * per, n);
  const unsigned short* gsl = gb + h * 128;
  unsigned short* pout = partial + (size_t)h * n * 128;
  const int g = lane >> 4;                   // edge slot 0..3
  const int c8 = (lane & 15) * 8;            // 8-channel offset within head
  const char* gbase = (const char*)gsl + (c8 << 1);

#if HAVE_BF16DOT2
#define STORE_W(sv, wv) make_int2((sv) << 11, (int)f2us(wv))
#else
#define STORE_W(sv, wv) make_int2((sv) << 11, __float_as_int(wv))
#endif

  for (int v = nblk * per + wave; v < v1; v += 4) {
    const int begin = row_ptr[v];
    const int deg = row_ptr[v + 1] - begin;
    const float edv = ed[(size_t)v * 8 + h];
    float acc[8];
#pragma unroll
    for (int k = 0; k < 8; k++) acc[k] = 0.f;

    auto gather16 = [&](int j0) {
      int2 e0 = swlds[wave][j0 + g];
      int2 e1 = swlds[wave][j0 + 4 + g];
      int2 e2 = swlds[wave][j0 + 8 + g];
      int2 e3 = swlds[wave][j0 + 12 + g];
      uint4 u0 = *(const uint4*)(gbase + (unsigned)e0.x);
      uint4 u1 = *(const uint4*)(gbase + (unsigned)e1.x);
      uint4 u2 = *(const uint4*)(gbase + (unsigned)e2.x);
      uint4 u3 = *(const uint4*)(gbase + (unsigned)e3.x);
#if HAVE_BF16DOT2
      bfv2 w01 = u2bf2(((unsigned)e0.y & 0xffffu) | ((unsigned)e1.y << 16));
      bfv2 w23 = u2bf2(((unsigned)e2.y & 0xffffu) | ((unsigned)e3.y << 16));
#define DOT2W(wa, wb, k0)                                                        \
      acc[k0]     = __builtin_amdgcn_fdot2_f32_bf16(                             \
          u2bf2(__builtin_amdgcn_perm(wb, wa, 0x05040100u)), w01, acc[k0], false); \
      acc[k0 + 1] = __builtin_amdgcn_fdot2_f32_bf16(                             \
          u2bf2(__builtin_amdgcn_perm(wb, wa, 0x07060302u)), w01, acc[k0 + 1], false);
#define DOT2X(wa, wb, k0)                                                        \
      acc[k0]     = __builtin_amdgcn_fdot2_f32_bf16(                             \
          u2bf2(__builtin_amdgcn_perm(wb, wa, 0x05040100u)), w23, acc[k0], false); \
      acc[k0 + 1] = __builtin_amdgcn_fdot2_f32_bf16(                             \
          u2bf2(__builtin_amdgcn_perm(wb, wa, 0x07060302u)), w23, acc[k0 + 1], false);
      DOT2W(u0.x, u1.x, 0) DOT2W(u0.y, u1.y, 2) DOT2W(u0.z, u1.z, 4) DOT2W(u0.w, u1.w, 6)
      DOT2X(u2.x, u3.x, 0) DOT2X(u2.y, u3.y, 2) DOT2X(u2.z, u3.z, 4) DOT2X(u2.w, u3.w, 6)
#undef DOT2W
#undef DOT2X
#else
      float w0 = __int_as_float(e0.y), w1 = __int_as_float(e1.y);
      float w2 = __int_as_float(e2.y), w3 = __int_as_float(e3.y);
      const ushort8 s0 = *(const ushort8*)&u0;
      const ushort8 s1 = *(const ushort8*)&u1;
      const ushort8 s2 = *(const ushort8*)&u2;
      const ushort8 s3 = *(const ushort8*)&u3;
#pragma unroll
      for (int k = 0; k < 8; k++) {
        acc[k] += w0 * bf2f(s0[k]) + w1 * bf2f(s1[k])
                + w2 * bf2f(s2[k]) + w3 * bf2f(s3[k]);
      }
#endif
    };

    if (deg <= 64) {
      int sv = 0; float a = -1e30f;
      if (lane < deg) {
        sv = srcs[begin + lane];
        float t = es[(size_t)sv * 8 + h] + edv;
        a = t > 0.f ? t : 0.2f * t;
      }
      float m = a;
#pragma unroll
      for (int off = 32; off > 0; off >>= 1) m = fmaxf(m, __shfl_xor(m, off));
      float p = __expf(a - m);
      float ds = p;
#pragma unroll
      for (int off = 32; off > 0; off >>= 1) ds += __shfl_xor(ds, off);
      float wv = p * (1.0f / (ds + 1e-16f));
      swlds[wave][lane] = STORE_W(sv, wv);

      const int npad = (deg + 15) & ~15;
      for (int j0 = 0; j0 < npad; j0 += 16) gather16(j0);
    } else {
      float m = -1e30f;
      for (int base = 0; base < deg; base += 64) {
        if (base + lane < deg) {
          int s = srcs[begin + base + lane];
          float t = es[(size_t)s * 8 + h] + edv;
          t = t > 0.f ? t : 0.2f * t;
          m = fmaxf(m, t);
        }
      }
#pragma unroll
      for (int off = 32; off > 0; off >>= 1) m = fmaxf(m, __shfl_xor(m, off));
      float ds = 0.f;
      for (int base = 0; base < deg; base += 64) {
        if (base + lane < deg) {
          int s = srcs[begin + base + lane];
          float t = es[(size_t)s * 8 + h] + edv;
          t = t > 0.f ? t : 0.2f * t;
          ds += __expf(t - m);
        }
      }
#pragma unroll
      for (int off = 32; off > 0; off >>= 1) ds += __shfl_xor(ds, off);
      const float invd = 1.0f / (ds + 1e-16f);

      for (int base = 0; base < deg; base += 64) {
        const int cnt = min(64, deg - base);
        int sv = 0; float wv = 0.f;
        if (lane < cnt) {
          sv = srcs[begin + base + lane];
          float t = es[(size_t)sv * 8 + h] + edv;
          t = t > 0.f ? t : 0.2f * t;
          wv = __expf(t - m) * invd;
        }
        swlds[wave][lane] = STORE_W(sv, wv);
        const int npad = (cnt + 15) & ~15;
        for (int j0 = 0; j0 < npad; j0 += 16) gather16(j0);
      }
    }

#pragma unroll
    for (int k = 0; k < 8; k++) {
      acc[k] += __shfl_xor(acc[k], 16);
      acc[k] += __shfl_xor(acc[k], 32);
    }
    if (lane < 16) {
      unsigned int o[4];
#pragma unroll
      for (int k = 0; k < 4; k++)
        o[k] = (unsigned int)f2us(acc[2 * k]) | ((unsigned int)f2us(acc[2 * k + 1]) << 16);
      *(uint4*)&pout[(size_t)v * 128 + c8] = *(uint4*)o;
    }
  }
#undef STORE_W
}

// ---------------------------------------------------------------------------
// Fused: reduce 8 head partials -> out, plus BN column sums.
// ---------------------------------------------------------------------------
__global__ __launch_bounds__(256) void gat_reduce_bn_kernel(
    const unsigned short* __restrict__ partial, const float* __restrict__ bias,
    float* __restrict__ out, float* __restrict__ sums, int n) {
  const int t = threadIdx.x;
  const int stride = gridDim.x * TPB;
  float s0 = 0.f, q0 = 0.f, s1 = 0.f, q1 = 0.f;
  for (int idx = blockIdx.x * TPB + t; idx < n * 64; idx += stride) {
    int v = idx >> 6, c = (idx & 63) * 2;
    float sx = 0.f, sy = 0.f;
#pragma unroll
    for (int h = 0; h < 8; h++) {
      unsigned int u = *(const unsigned int*)&partial[(size_t)h * n * 128 + (size_t)v * 128 + c];
      sx += bf2f((unsigned short)u);
      sy += bf2f((unsigned short)(u >> 16));
    }
    float x0 = sx * 0.125f + bias[c];
    float x1 = sy * 0.125f + bias[c + 1];
    out[(size_t)v * 128 + c]     = x0;
    out[(size_t)v * 128 + c + 1] = x1;
    s0 += x0; q0 += x0 * x0;
    s1 += x1; q1 += x1 * x1;
  }
  __shared__ float ls0[TPB], lq0[TPB], ls1[TPB], lq1[TPB];
  ls0[t] = s0; lq0[t] = q0; ls1[t] = s1; lq1[t] = q1;
  __syncthreads();
  if (t < 64) {
    float S0 = ls0[t] + ls0[t + 64] + ls0[t + 128] + ls0[t + 192];
    float Q0 = lq0[t] + lq0[t + 64] + lq0[t + 128] + lq0[t + 192];
    float S1 = ls1[t] + ls1[t + 64] + ls1[t + 128] + ls1[t + 192];
    float Q1 = lq1[t] + lq1[t + 64] + lq1[t + 128] + lq1[t + 192];
    int c = t * 2;
    atomicAdd(&sums[c], S0);
    atomicAdd(&sums[128 + c], Q0);
    atomicAdd(&sums[c + 1], S1);
    atomicAdd(&sums[128 + c + 1], Q1);
  }
}

// ---------------------------------------------------------------------------
// Layer-2 aggregation (H=1, C=64): one WAVE per dst node, dense g[N][64].
// ---------------------------------------------------------------------------
__global__ __launch_bounds__(256) void gat_aggregate1_kernel(
    const int* __restrict__ row_ptr, const int* __restrict__ srcs,
    const float* __restrict__ g, const float* __restrict__ es,
    const float* __restrict__ ed, const float* __restrict__ bias,
    float* __restrict__ out, int n) {
  const int wave = threadIdx.x >> 6;
  const int lane = threadIdx.x & 63;
  const int v = blockIdx.x * 4 + wave;

  __shared__ int2 swlds[4][64];

  if (v >= n) return;

  const int begin = row_ptr[v];
  const int deg = row_ptr[v + 1] - begin;
  const float edv = ed[v];
  const char* gbase = (const char*)g + lane * 4;

  float acc = 0.f;

  auto gather8 = [&](int j0) {
    int2 e0 = swlds[wave][j0 + 0], e1 = swlds[wave][j0 + 1];
    int2 e2 = swlds[wave][j0 + 2], e3 = swlds[wave][j0 + 3];
    int2 e4 = swlds[wave][j0 + 4], e5 = swlds[wave][j0 + 5];
    int2 e6 = swlds[wave][j0 + 6], e7 = swlds[wave][j0 + 7];
    float f0 = *(const float*)(gbase + (unsigned)e0.x);
    float f1 = *(const float*)(gbase + (unsigned)e1.x);
    float f2 = *(const float*)(gbase + (unsigned)e2.x);
    float f3 = *(const float*)(gbase + (unsigned)e3.x);
    float f4 = *(const float*)(gbase + (unsigned)e4.x);
    float f5 = *(const float*)(gbase + (unsigned)e5.x);
    float f6 = *(const float*)(gbase + (unsigned)e6.x);
    float f7 = *(const float*)(gbase + (unsigned)e7.x);
    acc += (__int_as_float(e0.y) * f0 + __int_as_float(e1.y) * f1)
         + (__int_as_float(e2.y) * f2 + __int_as_float(e3.y) * f3)
         + (__int_as_float(e4.y) * f4 + __int_as_float(e5.y) * f5)
         + (__int_as_float(e6.y) * f6 + __int_as_float(e7.y) * f7);
  };

  if (deg <= 64) {
    float a = -1e30f;
    int s = 0;
    if (lane < deg) {
      s = srcs[begin + lane];
      float t = es[s] + edv;
      a = t > 0.f ? t : 0.2f * t;
    }
    float m = a;
#pragma unroll
    for (int off = 32; off > 0; off >>= 1) m = fmaxf(m, __shfl_xor(m, off));
    float p = __expf(a - m);
    float dsum = p;
#pragma unroll
    for (int off = 32; off > 0; off >>= 1) dsum += __shfl_xor(dsum, off);
    const float invd = 1.0f / (dsum + 1e-16f);
    swlds[wave][lane] = make_int2(s << 8, __float_as_int(p * invd));

    const int npad = (deg + 7) & ~7;
    for (int j0 = 0; j0 < npad; j0 += 8) gather8(j0);
  } else {
    float pm = -1e30f;
    for (int j = lane; j < deg; j += 64) {
      float a = es[srcs[begin + j]] + edv;
      a = a > 0.f ? a : 0.2f * a;
      pm = fmaxf(pm, a);
    }
#pragma unroll
    for (int off = 32; off > 0; off >>= 1) pm = fmaxf(pm, __shfl_xor(pm, off));
    float ps = 0.f;
    for (int j = lane; j < deg; j += 64) {
      float a = es[srcs[begin + j]] + edv;
      a = a > 0.f ? a : 0.2f * a;
      ps += __expf(a - pm);
    }
#pragma unroll
    for (int off = 32; off > 0; off >>= 1) ps += __shfl_xor(ps, off);
    const float invd = 1.0f / (ps + 1e-16f);

    for (int base = 0; base < deg; base += 64) {
      int cnt = min(64, deg - base);
      float wv = 0.f; int s = 0;
      if (lane < cnt) {
        s = srcs[begin + base + lane];
        float a = es[s] + edv;
        a = a > 0.f ? a : 0.2f * a;
        wv = __expf(a - pm) * invd;
      }
      swlds[wave][lane] = make_int2(s << 8, __float_as_int(wv));
      const int npad = (cnt + 7) & ~7;
      for (int j0 = 0; j0 < npad; j0 += 8) gather8(j0);
    }
  }
  out[(size_t)v * 64 + lane] = acc + bias[lane];
}

// ---------------------------------------------------------------------------
// BN column stats (layer-2 only)
// ---------------------------------------------------------------------------
template <int C>
__global__ void bn_stats_kernel(const float* __restrict__ x, int n, float* __restrict__ sums) {
  constexpr int T = 256;
  constexpr int RPI = T / C;
  constexpr int ITER = 8;
  constexpr int ROWS = RPI * ITER;
  int c = threadIdx.x % C;
  int r0 = threadIdx.x / C;
  int rowBase = blockIdx.x * ROWS;
  float s = 0.f, q = 0.f;
  for (int it = 0; it < ITER; ++it) {
    int r = rowBase + it * RPI + r0;
    if (r < n) {
      float v = x[(size_t)r * C + c];
      s += v; q += v * v;
    }
  }
  __shared__ float ls[T], lq[T];
  ls[threadIdx.x] = s; lq[threadIdx.x] = q;
  __syncthreads();
  if (threadIdx.x < C) {
    float ts = 0.f, tq = 0.f;
    for (int r = 0; r < RPI; ++r) { ts += ls[c + r * C]; tq += lq[c + r * C]; }
    atomicAdd(&sums[c], ts);
    atomicAdd(&sums[C + c], tq);
  }
}

// ---------------------------------------------------------------------------
// out = elu(bn(x)) + res ; optional bf16 copy of out. res strided.
// ---------------------------------------------------------------------------
template <int C>
__global__ void bn_elu_res_kernel(const float* __restrict__ x, const float* __restrict__ sums,
                                  const float* __restrict__ gamma, const float* __restrict__ beta,
                                  const float* __restrict__ res, int res_stride,
                                  float* __restrict__ out, __hip_bfloat16* __restrict__ outb, int n) {
  int i = blockIdx.x * TPB + threadIdx.x;
  if (i >= n * C) return;
  int c = i % C;
  float inv_n = 1.0f / (float)n;
  float mu = sums[c] * inv_n;
  float var = sums[C + c] * inv_n - mu * mu;
  float y = (x[i] - mu) * rsqrtf(var + 1e-5f) * gamma[c] + beta[c];
  y = y > 0.f ? y : expm1f(y);
  y += res[(size_t)(i / C) * res_stride + c];
  out[i] = y;
  if (outb) outb[i] = __float2bfloat16(y);
}

// ---------------------------------------------------------------------------
// host launch
// ---------------------------------------------------------------------------
extern "C" void kernel_launch(void* const* d_in, const int* in_sizes, int n_in,
                              void* d_out, int out_size, void* d_ws, size_t ws_size,
                              hipStream_t stream) {
  const float* x   = (const float*)d_in[0];
  const void*  ei  = d_in[1];
  const float* Wp  = (const float*)d_in[2];
  const float* bp  = (const float*)d_in[3];
  const float* W0  = (const float*)d_in[4];
  const float* as0 = (const float*)d_in[5];
  const float* ad0 = (const float*)d_in[6];
  const float* b0  = (const float*)d_in[7];
  const float* g0  = (const float*)d_in[8];
  const float* be0 = (const float*)d_in[9];
  const float* W1  = (const float*)d_in[10];
  const float* as1 = (const float*)d_in[11];
  const float* ad1 = (const float*)d_in[12];
  const float* b1  = (const float*)d_in[13];
  const float* g1  = (const float*)d_in[14];
  const float* be1 = (const float*)d_in[15];
  const float* W2  = (const float*)d_in[16];
  const float* as2 = (const float*)d_in[17];
  const float* ad2 = (const float*)d_in[18];
  const float* b2  = (const float*)d_in[19];
  const float* g2  = (const float*)d_in[20];
  const float* be2 = (const float*)d_in[21];
  const float* Wr  = (const float*)d_in[22];
  const float* br  = (const float*)d_in[23];

  const int N = in_sizes[0] / 64;       // 10000
  const int E = in_sizes[1] / 2;        // 160000
  const int ETOT = E + N;

  char* wsp = (char*)d_ws;
  size_t off = 0;
  auto alloc = [&](size_t bytes) -> void* {
    void* p = wsp + off;
    off += (bytes + 255) & ~(size_t)255;
    return p;
  };
  int*   flag    = (int*)alloc(4);
  int*   e_src   = (int*)alloc((size_t)ETOT * 4);
  int*   e_dst   = (int*)alloc((size_t)ETOT * 4);
  int*   counts  = (int*)alloc((size_t)N * 4);
  int*   fillc   = (int*)alloc((size_t)N * 4);
  int*   row_ptr = (int*)alloc((size_t)(N + 1) * 4);
  int*   s_src   = (int*)alloc((size_t)ETOT * 4);
  float* hA      = (float*)alloc((size_t)N * 128 * 4);
  float* hB      = (float*)alloc((size_t)N * 128 * 4);
  float* gat     = (float*)alloc((size_t)N * 128 * 4);
  float* es      = (float*)alloc((size_t)N * 8 * 4);
  float* ed      = (float*)alloc((size_t)N * 8 * 4);
  float* bnsum   = (float*)alloc(2 * 128 * 4);
  __hip_bfloat16* gbufb = (__hip_bfloat16*)alloc((size_t)N * 1024 * 2);  // big-layer g (bf16)
  float* gbuf    = (float*)gbufb;                                   // layer-2 g (f32, aliased)
  unsigned short* partial = (unsigned short*)alloc((size_t)N * 1024 * 2); // [8][N][128] bf16
  __hip_bfloat16* xb  = (__hip_bfloat16*)alloc((size_t)N * 64 * 2);
  __hip_bfloat16* hAb = (__hip_bfloat16*)alloc((size_t)N * 128 * 2);
  __hip_bfloat16* hBb = (__hip_bfloat16*)alloc((size_t)N * 128 * 2);
  __hip_bfloat16* WpT = (__hip_bfloat16*)alloc((size_t)128 * 64 * 2);    // [128][64]
  __hip_bfloat16* W0T = (__hip_bfloat16*)alloc((size_t)1024 * 128 * 2);  // [1024][128]
  __hip_bfloat16* W1T = (__hip_bfloat16*)alloc((size_t)1024 * 128 * 2);
  __hip_bfloat16* WrW2T = (__hip_bfloat16*)alloc((size_t)128 * 128 * 2); // [Wr rows 0-63 | W2 rows 64-127]

  const int egrid = (ETOT + TPB - 1) / TPB;
  const int mgrid = (N + 63) / 64;      // 157
  const int NB = 512;                   // node-blocks for head-gather (4096 blocks)
  auto cgrid = [](int n) { return (n + TPB - 1) / TPB; };

  // ---- graph prep ----
  prep_kernel<<<cgrid(N), TPB, 0, stream>>>((const unsigned int*)ei, flag, counts, fillc, N);
  decode_count_kernel<<<egrid, TPB, 0, stream>>>(ei, flag, e_src, e_dst, counts, E, N);
  scan_kernel<<<1, TPB, 0, stream>>>(counts, row_ptr, N);
  fill_kernel<<<egrid, TPB, 0, stream>>>(e_src, e_dst, row_ptr, fillc, s_src, ETOT);

  // ---- conversions (batched) ----
  f32_to_bf16_kernel<<<cgrid(N * 64), TPB, 0, stream>>>(x, xb, N * 64);
  convert_weights_kernel<<<280, 256, 0, stream>>>(Wp, W0, W1, W2, Wr, WpT, W0T, W1T, WrW2T);

  // ---- projection: hA = x @ Wp + bp (also bf16 copy hAb) ----
  gemm_bf16t_kernel<<<dim3(mgrid, 1), 256, 0, stream>>>(
      (const short*)xb, (const short*)WpT, bp, hA, hAb, N, 128, 64,
      nullptr, nullptr, nullptr, nullptr, 1, 7, nullptr, 0);

  // ---- layer 0 ----
  gemm_bf16t_kernel<<<dim3(mgrid, 8), 256, 0, stream>>>(
      (const short*)hAb, (const short*)W0T, nullptr, nullptr, gbufb, N, 1024, 128,
      as0, ad0, es, ed, 8, 7, bnsum, 256);
  gat_gather_head_kernel<<<8 * NB, 256, 0, stream>>>(
      row_ptr, s_src, (const unsigned short*)gbufb, es, ed, partial, N, NB);
  gat_reduce_bn_kernel<<<512, 256, 0, stream>>>(partial, b0, gat, bnsum, N);
  bn_elu_res_kernel<128><<<cgrid(N * 128), TPB, 0, stream>>>(
      gat, bnsum, g0, be0, hA, 128, hB, hBb, N);

  // ---- layer 1 ----
  gemm_bf16t_kernel<<<dim3(mgrid, 8), 256, 0, stream>>>(
      (const short*)hBb, (const short*)W1T, nullptr, nullptr, gbufb, N, 1024, 128,
      as1, ad1, es, ed, 8, 7, bnsum, 256);
  gat_gather_head_kernel<<<8 * NB, 256, 0, stream>>>(
      row_ptr, s_src, (const unsigned short*)gbufb, es, ed, partial, N, NB);
  gat_reduce_bn_kernel<<<512, 256, 0, stream>>>(partial, b1, gat, bnsum, N);
  bn_elu_res_kernel<128><<<cgrid(N * 128), TPB, 0, stream>>>(
      gat, bnsum, g1, be1, hB, 128, hA, hAb, N);

  // ---- layer 2 (H=1, C=64): two dense GEMMs (Wr half / W2 half of WrW2T) ----
  gemm_bf16t_kernel<<<dim3(mgrid, 1), 256, 0, stream>>>(
      (const short*)hAb, (const short*)WrW2T, br, hB, nullptr, N, 64, 128,
      nullptr, nullptr, nullptr, nullptr, 1, 7, nullptr, 0);              // hr -> hB[N][64]
  gemm_bf16t_kernel<<<dim3(mgrid, 1), 256, 0, stream>>>(
      (const short*)hAb, (const short*)(WrW2T + 64 * 128), nullptr, gbuf, nullptr, N, 64, 128,
      as2, ad2, es, ed, 1, 6, bnsum, 128);                                // g -> gbuf[N][64]
  gat_aggregate1_kernel<<<(N + 3) / 4, 256, 0, stream>>>(
      row_ptr, s_src, gbuf, es, ed, b2, gat, N);
  bn_stats_kernel<64><<<(N + 31) / 32, 256, 0, stream>>>(gat, N, bnsum);
  bn_elu_res_kernel<64><<<cgrid(N * 64), TPB, 0, stream>>>(
      gat, bnsum, g2, be2, hB, 64, (float*)d_out, nullptr, N);
}